// Round 3
// baseline (1157.929 us; speedup 1.0000x reference)
//
#include <hip/hip_runtime.h>

typedef unsigned int uint;
typedef unsigned short ushort;
typedef __attribute__((ext_vector_type(8))) short bhalf8;
typedef __attribute__((ext_vector_type(4))) float floatx4;

#define D_IN 256
#define HSZ 512
#define GATESN 2048
#define NSUP 512
#define BATCH_N 32768
#define KCAT 768
#define MHALF 16384

__device__ __forceinline__ ushort f2b(float f){
  union { float f; uint u; } x; x.f = f;
  uint r = (x.u + 0x7fffu + ((x.u >> 16) & 1u)) >> 16;
  return (ushort)r;
}
__device__ __forceinline__ float b2f(ushort u){
  union { uint u; float f; } x; x.u = ((uint)u) << 16;
  return x.f;
}
__device__ __forceinline__ float sigmf(float x){ return 1.0f / (1.0f + __expf(-x)); }

// ---------------------------------------------------------------------------
// Generic C = A * B^T GEMM, bf16 in, fp32/bf16 out. 128x128 tile, 4 waves,
// BK=64, mfma_f32_16x16x32_bf16. M,N multiples of 128; K multiple of 64.
// ---------------------------------------------------------------------------
#define BKD 64
#define LDP 72   // BK + 8 pad to break 16-way LDS bank conflict

template<int OUT_BF16>
__global__ __launch_bounds__(256) void gemm_bt(
    const ushort* __restrict__ A, int lda,
    const ushort* __restrict__ B, int ldb,
    void* __restrict__ Cv, int ldc,
    int K, int nbn)
{
  __shared__ ushort As[128 * LDP];
  __shared__ ushort Bs[128 * LDP];

  const int tid  = threadIdx.x;
  const int lane = tid & 63;
  const int wave = tid >> 6;
  const int wr = (wave >> 1) * 64;
  const int wc = (wave & 1) * 64;
  const int bm = blockIdx.x / nbn;
  const int bn = blockIdx.x % nbn;
  const int rowA0 = bm * 128;
  const int rowB0 = bn * 128;

  floatx4 acc[4][4];
  #pragma unroll
  for (int m = 0; m < 4; m++)
    #pragma unroll
    for (int n = 0; n < 4; n++)
      acc[m][n] = (floatx4){0.f, 0.f, 0.f, 0.f};

  const int srow = tid >> 3;
  const int skk  = (tid & 7) << 3;
  const int lr = lane & 15;
  const int lk = (lane >> 4) << 3;

  for (int k0 = 0; k0 < K; k0 += BKD) {
    #pragma unroll
    for (int q = 0; q < 4; q++) {
      int r = srow + q * 32;
      uint4 va = *reinterpret_cast<const uint4*>(A + (long)(rowA0 + r) * lda + k0 + skk);
      uint4 vb = *reinterpret_cast<const uint4*>(B + (long)(rowB0 + r) * ldb + k0 + skk);
      *reinterpret_cast<uint4*>(&As[r * LDP + skk]) = va;
      *reinterpret_cast<uint4*>(&Bs[r * LDP + skk]) = vb;
    }
    __syncthreads();
    #pragma unroll
    for (int ks = 0; ks < 2; ks++) {
      bhalf8 af[4], bfr[4];
      #pragma unroll
      for (int m = 0; m < 4; m++)
        af[m] = *reinterpret_cast<const bhalf8*>(&As[(wr + m * 16 + lr) * LDP + ks * 32 + lk]);
      #pragma unroll
      for (int n = 0; n < 4; n++)
        bfr[n] = *reinterpret_cast<const bhalf8*>(&Bs[(wc + n * 16 + lr) * LDP + ks * 32 + lk]);
      #pragma unroll
      for (int m = 0; m < 4; m++)
        #pragma unroll
        for (int n = 0; n < 4; n++)
          acc[m][n] = __builtin_amdgcn_mfma_f32_16x16x32_bf16(af[m], bfr[n], acc[m][n], 0, 0, 0);
    }
    __syncthreads();
  }

  const int lg = lane >> 4;
  #pragma unroll
  for (int m = 0; m < 4; m++) {
    #pragma unroll
    for (int n = 0; n < 4; n++) {
      #pragma unroll
      for (int r = 0; r < 4; r++) {
        int row = rowA0 + wr + m * 16 + lg * 4 + r;
        int col = rowB0 + wc + n * 16 + lr;
        float v = acc[m][n][r];
        if (OUT_BF16)
          ((ushort*)Cv)[(long)row * ldc + col] = f2b(v);
        else
          ((float*)Cv)[(long)row * ldc + col] = v;
      }
    }
  }
}

// ---------------------------------------------------------------------------
// Split-precision scores GEMM: C = (Ahi+Alo) @ (Bhi+Blo)^T, dropping lo*lo.
// Ahi read from A_cat (lda 768), Alo separate (lda 256). C fp32 [32768,512].
// ---------------------------------------------------------------------------
__global__ __launch_bounds__(256) void gemm_scores(
    const ushort* __restrict__ Ahi, int ldah,
    const ushort* __restrict__ Alo, int ldal,
    const ushort* __restrict__ Bhi, const ushort* __restrict__ Blo,
    float* __restrict__ C)
{
  __shared__ ushort AsH[128 * LDP];
  __shared__ ushort AsL[128 * LDP];
  __shared__ ushort BsH[128 * LDP];
  __shared__ ushort BsL[128 * LDP];

  const int tid  = threadIdx.x;
  const int lane = tid & 63;
  const int wave = tid >> 6;
  const int wr = (wave >> 1) * 64;
  const int wc = (wave & 1) * 64;
  const int bm = blockIdx.x >> 2;      // NSUP/128 = 4
  const int bn = blockIdx.x & 3;
  const int rowA0 = bm * 128;
  const int rowB0 = bn * 128;

  floatx4 acc[4][4];
  #pragma unroll
  for (int m = 0; m < 4; m++)
    #pragma unroll
    for (int n = 0; n < 4; n++)
      acc[m][n] = (floatx4){0.f, 0.f, 0.f, 0.f};

  const int srow = tid >> 3;
  const int skk  = (tid & 7) << 3;
  const int lr = lane & 15;
  const int lk = (lane >> 4) << 3;

  for (int k0 = 0; k0 < D_IN; k0 += BKD) {
    #pragma unroll
    for (int q = 0; q < 4; q++) {
      int r = srow + q * 32;
      *reinterpret_cast<uint4*>(&AsH[r * LDP + skk]) =
          *reinterpret_cast<const uint4*>(Ahi + (long)(rowA0 + r) * ldah + k0 + skk);
      *reinterpret_cast<uint4*>(&AsL[r * LDP + skk]) =
          *reinterpret_cast<const uint4*>(Alo + (long)(rowA0 + r) * ldal + k0 + skk);
      *reinterpret_cast<uint4*>(&BsH[r * LDP + skk]) =
          *reinterpret_cast<const uint4*>(Bhi + (long)(rowB0 + r) * D_IN + k0 + skk);
      *reinterpret_cast<uint4*>(&BsL[r * LDP + skk]) =
          *reinterpret_cast<const uint4*>(Blo + (long)(rowB0 + r) * D_IN + k0 + skk);
    }
    __syncthreads();
    #pragma unroll
    for (int ks = 0; ks < 2; ks++) {
      bhalf8 afh[4], afl[4], bfh[4], bfl[4];
      #pragma unroll
      for (int m = 0; m < 4; m++) {
        afh[m] = *reinterpret_cast<const bhalf8*>(&AsH[(wr + m * 16 + lr) * LDP + ks * 32 + lk]);
        afl[m] = *reinterpret_cast<const bhalf8*>(&AsL[(wr + m * 16 + lr) * LDP + ks * 32 + lk]);
      }
      #pragma unroll
      for (int n = 0; n < 4; n++) {
        bfh[n] = *reinterpret_cast<const bhalf8*>(&BsH[(wc + n * 16 + lr) * LDP + ks * 32 + lk]);
        bfl[n] = *reinterpret_cast<const bhalf8*>(&BsL[(wc + n * 16 + lr) * LDP + ks * 32 + lk]);
      }
      #pragma unroll
      for (int m = 0; m < 4; m++)
        #pragma unroll
        for (int n = 0; n < 4; n++) {
          acc[m][n] = __builtin_amdgcn_mfma_f32_16x16x32_bf16(afl[m], bfh[n], acc[m][n], 0, 0, 0);
          acc[m][n] = __builtin_amdgcn_mfma_f32_16x16x32_bf16(afh[m], bfl[n], acc[m][n], 0, 0, 0);
          acc[m][n] = __builtin_amdgcn_mfma_f32_16x16x32_bf16(afh[m], bfh[n], acc[m][n], 0, 0, 0);
        }
    }
    __syncthreads();
  }

  const int lg = lane >> 4;
  #pragma unroll
  for (int m = 0; m < 4; m++)
    #pragma unroll
    for (int n = 0; n < 4; n++)
      #pragma unroll
      for (int r = 0; r < 4; r++) {
        int row = rowA0 + wr + m * 16 + lg * 4 + r;
        int col = rowB0 + wc + n * 16 + lr;
        C[(long)row * NSUP + col] = acc[m][n][r];
      }
}

// ---------------------------------------------------------------------------
// Build fused weight [W_hh | W_ih] bf16 [2048,768], bias sum, S hi/lo, S^T bf16
// ---------------------------------------------------------------------------
__global__ __launch_bounds__(256) void k_build(
    const float* __restrict__ Wih, const float* __restrict__ Whh,
    const float* __restrict__ bih, const float* __restrict__ bhh,
    const float* __restrict__ S,
    ushort* __restrict__ Wcat, float* __restrict__ bias,
    ushort* __restrict__ Shi, ushort* __restrict__ Slo,
    ushort* __restrict__ STb)
{
  int t = blockIdx.x * 256 + threadIdx.x;
  if (t < GATESN * KCAT) {
    int n = t / KCAT, k = t % KCAT;
    float v = (k < HSZ) ? Whh[(long)n * HSZ + k] : Wih[(long)n * D_IN + (k - HSZ)];
    Wcat[t] = f2b(v);
  }
  if (t < GATESN) bias[t] = bih[t] + bhh[t];
  if (t < NSUP * D_IN) {
    float v = S[t];
    ushort hv = f2b(v);
    Shi[t] = hv;
    Slo[t] = f2b(v - b2f(hv));
    int s = t >> 8, d = t & 255;
    STb[(long)d * NSUP + s] = hv;
  }
}

// A_cat = [h(0:256) | r(256:512) | query(512:768)] bf16 ; zero h,r ; c = 0
__global__ __launch_bounds__(256) void k_initA(
    const float* __restrict__ query, ushort* __restrict__ Abuf, float* __restrict__ c)
{
  long t = (long)blockIdx.x * 256 + threadIdx.x;
  const long nA = (long)BATCH_N * KCAT;
  if (t < nA) {
    int b = (int)(t / KCAT), col = (int)(t % KCAT);
    Abuf[t] = (col < HSZ) ? (ushort)0 : f2b(query[(long)b * D_IN + (col - HSZ)]);
  } else {
    c[t - nA] = 0.f;
  }
}

// ---------------------------------------------------------------------------
// LSTM pointwise on one M-half: gates bf16 [MHALF,2048] (+bias) -> c update;
// h = query + o*tanh(c) -> bf16 hi into A_cat[:,0:256], lo into Hlo.
// All row pointers pre-offset by the half. 2 elems/thread, 1 block/row.
// ---------------------------------------------------------------------------
__global__ __launch_bounds__(256) void k_lstm(
    const ushort* __restrict__ gates, const float* __restrict__ bias,
    float* __restrict__ c, const float* __restrict__ query,
    ushort* __restrict__ Abuf, ushort* __restrict__ Hlo)
{
  int b = blockIdx.x;
  int j = threadIdx.x << 1;
  const ushort* g = gates + (long)b * GATESN + j;
  uint ri = *(const uint*)(g);
  uint rf = *(const uint*)(g + 512);
  uint rg = *(const uint*)(g + 1024);
  uint ro = *(const uint*)(g + 1536);
  float* cp = c + (long)b * HSZ + j;
  float2 cc  = *(const float2*)cp;
  float2 bi  = *(const float2*)(bias + j);
  float2 bf2 = *(const float2*)(bias + 512 + j);
  float2 bg2 = *(const float2*)(bias + 1024 + j);
  float2 bo2 = *(const float2*)(bias + 1536 + j);

  float i0 = sigmf(b2f((ushort)(ri & 0xffff)) + bi.x);
  float i1 = sigmf(b2f((ushort)(ri >> 16))    + bi.y);
  float f0 = sigmf(b2f((ushort)(rf & 0xffff)) + bf2.x);
  float f1 = sigmf(b2f((ushort)(rf >> 16))    + bf2.y);
  float g0 = tanhf(b2f((ushort)(rg & 0xffff)) + bg2.x);
  float g1 = tanhf(b2f((ushort)(rg >> 16))    + bg2.y);
  float o0 = sigmf(b2f((ushort)(ro & 0xffff)) + bo2.x);
  float o1 = sigmf(b2f((ushort)(ro >> 16))    + bo2.y);

  float c0 = f0 * cc.x + i0 * g0;
  float c1 = f1 * cc.y + i1 * g1;
  *(float2*)cp = make_float2(c0, c1);

  if (j < D_IN) {
    float2 q2 = *(const float2*)(query + (long)b * D_IN + j);
    float h0 = q2.x + o0 * tanhf(c0);
    float h1 = q2.y + o1 * tanhf(c1);
    ushort h0h = f2b(h0), h1h = f2b(h1);
    ushort h0l = f2b(h0 - b2f(h0h)), h1l = f2b(h1 - b2f(h1h));
    *(uint*)(Abuf + (long)b * KCAT + j) = (uint)h0h | ((uint)h1h << 16);
    *(uint*)(Hlo + (long)b * D_IN + j) = (uint)h0l | ((uint)h1l << 16);
  }
}

// ---------------------------------------------------------------------------
// Row softmax over 512 cols, fp32 in, bf16 out. 1 wave / row.
// ---------------------------------------------------------------------------
__global__ __launch_bounds__(256) void k_softmax(
    const float* __restrict__ sc, ushort* __restrict__ attn)
{
  int row  = blockIdx.x * 4 + (threadIdx.x >> 6);
  int lane = threadIdx.x & 63;
  const float4* sp = reinterpret_cast<const float4*>(sc + (long)row * NSUP);
  float4 v0 = sp[lane];
  float4 v1 = sp[64 + lane];
  float m = fmaxf(fmaxf(fmaxf(v0.x, v0.y), fmaxf(v0.z, v0.w)),
                  fmaxf(fmaxf(v1.x, v1.y), fmaxf(v1.z, v1.w)));
  #pragma unroll
  for (int off = 32; off >= 1; off >>= 1) m = fmaxf(m, __shfl_xor(m, off));
  float e0 = __expf(v0.x - m), e1 = __expf(v0.y - m), e2 = __expf(v0.z - m), e3 = __expf(v0.w - m);
  float e4 = __expf(v1.x - m), e5 = __expf(v1.y - m), e6 = __expf(v1.z - m), e7 = __expf(v1.w - m);
  float s = e0 + e1 + e2 + e3 + e4 + e5 + e6 + e7;
  #pragma unroll
  for (int off = 32; off >= 1; off >>= 1) s += __shfl_xor(s, off);
  float inv = 1.0f / s;
  uint2 p0, p1;
  p0.x = (uint)f2b(e0 * inv) | ((uint)f2b(e1 * inv) << 16);
  p0.y = (uint)f2b(e2 * inv) | ((uint)f2b(e3 * inv) << 16);
  p1.x = (uint)f2b(e4 * inv) | ((uint)f2b(e5 * inv) << 16);
  p1.y = (uint)f2b(e6 * inv) | ((uint)f2b(e7 * inv) << 16);
  uint2* ap = reinterpret_cast<uint2*>(attn + (long)row * NSUP);
  ap[lane] = p0;
  ap[64 + lane] = p1;
}

// ---------------------------------------------------------------------------
extern "C" void kernel_launch(void* const* d_in, const int* in_sizes, int n_in,
                              void* d_out, int out_size, void* d_ws, size_t ws_size,
                              hipStream_t stream)
{
  const float* support_mean = (const float*)d_in[0];
  const float* query_mean   = (const float*)d_in[2];
  const float* W_ih = (const float*)d_in[4];
  const float* W_hh = (const float*)d_in[5];
  const float* b_ih = (const float*)d_in[6];
  const float* b_hh = (const float*)d_in[7];
  float* out = (float*)d_out;

  char* ws = (char*)d_ws;
  size_t off = 0;
  auto alloc = [&](size_t bytes) {
    void* p = ws + off;
    off += (bytes + 255) & ~(size_t)255;
    return p;
  };
  ushort* Abuf  = (ushort*)alloc((size_t)BATCH_N * KCAT * 2);   // 50.3 MB
  ushort* Wcat  = (ushort*)alloc((size_t)GATESN * KCAT * 2);    // 3.1 MB
  float*  bias  = (float*) alloc((size_t)GATESN * 4);
  ushort* Shi   = (ushort*)alloc((size_t)NSUP * D_IN * 2);
  ushort* Slo   = (ushort*)alloc((size_t)NSUP * D_IN * 2);
  ushort* STb   = (ushort*)alloc((size_t)D_IN * NSUP * 2);
  float*  cbuf  = (float*) alloc((size_t)BATCH_N * HSZ * 4);    // 67.1 MB
  ushort* Hlo   = (ushort*)alloc((size_t)BATCH_N * D_IN * 2);   // 16.8 MB
  ushort* gates = (ushort*)alloc((size_t)MHALF * GATESN * 2);   // 67.1 MB (half-M)
  ushort* attn  = gates;  // alias: attn lives softmax->pv; gates dead by then
  if (off > ws_size) return;  // total ~205.3 MB; round-1 proved >=255 MB exists

  hipLaunchKernelGGL(k_build, dim3((GATESN * KCAT) / 256), dim3(256), 0, stream,
                     W_ih, W_hh, b_ih, b_hh, support_mean, Wcat, bias, Shi, Slo, STb);
  hipLaunchKernelGGL(k_initA, dim3((BATCH_N * (KCAT + HSZ)) / 256), dim3(256), 0, stream,
                     query_mean, Abuf, cbuf);

  for (int step = 0; step < 4; step++) {
    // gates = A_cat @ Wcat^T in two M-halves to bound workspace
    for (int half = 0; half < 2; half++) {
      const long r0 = (long)half * MHALF;
      hipLaunchKernelGGL(gemm_bt<1>, dim3((MHALF / 128) * (GATESN / 128)), dim3(256), 0, stream,
                         Abuf + r0 * KCAT, KCAT, Wcat, KCAT, (void*)gates, GATESN,
                         KCAT, GATESN / 128);
      hipLaunchKernelGGL(k_lstm, dim3(MHALF), dim3(256), 0, stream,
                         gates, bias, cbuf + r0 * HSZ, query_mean + r0 * D_IN,
                         Abuf + r0 * KCAT, Hlo + r0 * D_IN);
    }
    // scores = h @ S^T (split precision) -> d_out fp32
    hipLaunchKernelGGL(gemm_scores, dim3((BATCH_N / 128) * (NSUP / 128)), dim3(256), 0, stream,
                       Abuf, KCAT, Hlo, D_IN, Shi, Slo, out);
    if (step < 3) {
      hipLaunchKernelGGL(k_softmax, dim3(BATCH_N / 4), dim3(256), 0, stream, out, attn);
      // r = attn @ S  -> bf16 into A_cat[:,256:512]
      hipLaunchKernelGGL(gemm_bt<1>, dim3((BATCH_N / 128) * (D_IN / 128)), dim3(256), 0, stream,
                         attn, NSUP, STb, NSUP, (void*)(Abuf + D_IN), KCAT, NSUP, D_IN / 128);
    }
  }
}